// Round 7
// baseline (225.917 us; speedup 1.0000x reference)
//
#include <hip/hip_runtime.h>
#include <hip/hip_bf16.h>
#include <math.h>

#define B_ 2
#define TX_ 1024
#define TY_ 4096
#define C_ 768
#define H_ 12
#define D_ 64
#define NSPLIT 2
#define R_ (B_ * H_ * TX_)

typedef __bf16 bf16x8 __attribute__((ext_vector_type(8)));
typedef float floatx4 __attribute__((ext_vector_type(4)));

__device__ __forceinline__ void async_copy16(const void* g, void* l) {
    __builtin_amdgcn_global_load_lds(
        (const __attribute__((address_space(1))) unsigned int*)g,
        (__attribute__((address_space(3))) unsigned int*)l,
        16, 0, 0);
}

__device__ __forceinline__ bf16x8 cvt8(const float* s) {
    bf16x8 r;
#pragma unroll
    for (int i = 0; i < 8; i++) r[i] = (__bf16)s[i];
    return r;
}

// ---------------------------------------------------------------------------
// fused transpose of all 3 weights: W(768 x N f32) -> Wt(N x 768 bf16)
// blockIdx.x: [0,24) Wq (x0.125) | [24,72) Wkv | [72,96) Wproj
// ---------------------------------------------------------------------------
__global__ __launch_bounds__(256)
void transp_all(const float* __restrict__ Wq,   __bf16* __restrict__ Wqt,
                const float* __restrict__ Wkv,  __bf16* __restrict__ Wkvt,
                const float* __restrict__ Wpr,  __bf16* __restrict__ Wprt)
{
    __shared__ float tile[32][33];
    const int bxr = blockIdx.x;
    const float* W; __bf16* Wt; int N, nb; float scale = 1.0f;
    if (bxr < 24)      { W = Wq;  Wt = Wqt;  N = C_;     nb = bxr;      scale = 0.125f; }
    else if (bxr < 72) { W = Wkv; Wt = Wkvt; N = 2 * C_; nb = bxr - 24; }
    else               { W = Wpr; Wt = Wprt; N = C_;     nb = bxr - 72; }
    const int bx = nb * 32;
    const int by = blockIdx.y * 32;
    const int tx = threadIdx.x & 31, ty = threadIdx.x >> 5;
#pragma unroll
    for (int i = 0; i < 4; i++)
        tile[ty + i * 8][tx] = W[(size_t)(by + ty + i * 8) * N + bx + tx];
    __syncthreads();
#pragma unroll
    for (int i = 0; i < 4; i++)
        Wt[(size_t)(bx + ty + i * 8) * C_ + by + tx] =
            (__bf16)(tile[tx][ty + i * 8] * scale);
}

// ---------------------------------------------------------------------------
// Fused Q + KV MFMA GEMM, 1D grid of 864 blocks (Q tiles FIRST so they mix
// with the first KV dispatch wave — no trailing low-occupancy tail).
//   bid <  96: Q  (A=x f32, Bt=Wqt):  rope -> Qbh [bh][TX][64] bf16
//   bid >= 96: KV (A=y f32, Bt=Wkvt): n0<C_ rope -> Kbh [bh][TY][64];
//              n0>=C_ -> Vtb [bh][64][TY] (transposed)
// A is staged f32->bf16 in-kernel (conv kernel eliminated); B via
// global_load_lds width 16.
// ---------------------------------------------------------------------------
__global__ __launch_bounds__(256)
void gemm_qkv(const float* __restrict__ xA, const __bf16* __restrict__ Wqt,
              const float* __restrict__ yA, const __bf16* __restrict__ Wkvt,
              __bf16* __restrict__ Qbh, __bf16* __restrict__ Kbh,
              __bf16* __restrict__ Vtb,
              const float* __restrict__ x_t, const float* __restrict__ y_t,
              const float* __restrict__ inv_freq)
{
    const int bid = blockIdx.x;
    const bool isQ = (bid < 96);
    const float* Af; const __bf16* Bt; const float* t_arr;
    int row0, n0, T, TSH;
    if (isQ) {
        Af = xA; Bt = Wqt; t_arr = x_t;
        row0 = (bid / 6) * 128; n0 = (bid % 6) * 128; T = TX_; TSH = 10;
    } else {
        const int r = bid - 96;
        Af = yA; Bt = Wkvt; t_arr = y_t;
        row0 = (r / 12) * 128; n0 = (r % 12) * 128; T = TY_; TSH = 12;
    }
    const bool isV = (!isQ) && (n0 >= C_);

    __shared__ __align__(16) float smem_f[4224];   // 16896 B
    __bf16* As = (__bf16*)smem_f;

    const int tid  = threadIdx.x;
    const int wave = tid >> 6;
    const int lane = tid & 63;
    const int m16  = lane & 15;
    const int quad = lane >> 4;
    const int wm   = wave >> 1;
    const int wn   = wave & 1;

    floatx4 acc[4][4];
#pragma unroll
    for (int i = 0; i < 4; i++)
#pragma unroll
        for (int j = 0; j < 4; j++) acc[i][j] = (floatx4){0.f, 0.f, 0.f, 0.f};

    int srow[4], scol[4];
#pragma unroll
    for (int j = 0; j < 4; j++) {
        int e = j * 2048 + wave * 512 + lane * 8;
        int e2 = e & 4095;
        srow[j] = e2 >> 5;
        scol[j] = e2 & 31;
    }

    for (int k0 = 0; k0 < C_; k0 += 32) {
        __syncthreads();
        // B: async global->LDS (bytes [8192,16384))
#pragma unroll
        for (int j = 2; j < 4; j++)
            async_copy16(Bt + (size_t)(n0 + srow[j]) * C_ + (k0 + scol[j]),
                         (char*)smem_f + j * 4096 + wave * 1024);
        // A: manual f32 load + convert + ds_write (bytes [0,8192))
#pragma unroll
        for (int j = 0; j < 2; j++) {
            const float* src = Af + (size_t)(row0 + srow[j]) * C_ + (k0 + scol[j]);
            float4 a0 = *(const float4*)src;
            float4 a1 = *(const float4*)(src + 4);
            bf16x8 v;
            v[0] = (__bf16)a0.x; v[1] = (__bf16)a0.y; v[2] = (__bf16)a0.z; v[3] = (__bf16)a0.w;
            v[4] = (__bf16)a1.x; v[5] = (__bf16)a1.y; v[6] = (__bf16)a1.z; v[7] = (__bf16)a1.w;
            *(bf16x8*)((char*)smem_f + j * 4096 + wave * 1024 + lane * 16) = v;
        }
        __syncthreads();

        bf16x8 af[4], bfr[4];
#pragma unroll
        for (int i = 0; i < 4; i++)
            af[i] = *(const bf16x8*)(As + (size_t)(wm * 64 + i * 16 + m16) * 32 + quad * 8);
#pragma unroll
        for (int j = 0; j < 4; j++)
            bfr[j] = *(const bf16x8*)(As + 4096 + (size_t)(wn * 64 + j * 16 + m16) * 32 + quad * 8);
#pragma unroll
        for (int i = 0; i < 4; i++)
#pragma unroll
            for (int j = 0; j < 4; j++)
                acc[i][j] = __builtin_amdgcn_mfma_f32_16x16x32_bf16(af[i], bfr[j], acc[i][j], 0, 0, 0);
    }

    // ---- epilogue (LDS-staged) ----
    const int STR = 132;
    float* fs = smem_f;

#pragma unroll
    for (int i = 0; i < 4; i++) {
        __syncthreads();
#pragma unroll
        for (int j = 0; j < 4; j++) {
            const int col_l = wn * 64 + j * 16 + m16;
#pragma unroll
            for (int r = 0; r < 4; r++) {
                const int row_l = quad * 4 + r;
                float v = acc[i][j][r];
                if (!isV) {
                    const float vp = __shfl_xor(v, 1);
                    const int row = row0 + wm * 64 + i * 16 + row_l;
                    const int cc = (n0 + col_l) & (D_ - 1);
                    const float fr = t_arr[row] * inv_freq[cc >> 1];
                    const float sn = __sinf(fr), cs = __cosf(fr);
                    v = (m16 & 1) ? (v * cs + vp * sn) : (v * cs - vp * sn);
                }
                fs[(wm * 16 + row_l) * STR + col_l] = v;
            }
        }
        __syncthreads();

        if (!isV) {
            // bf16 head-major [bh][T][64]
            __bf16* outb = isQ ? Qbh : Kbh;
            const int r32 = tid >> 3;
            const int lane8 = tid & 7;
            const int grow = row0 + (r32 >> 4) * 64 + i * 16 + (r32 & 15);
            const int bb = grow >> TSH;
            const int rk = grow & (T - 1);
            const int h  = (n0 >> 6) + (lane8 >> 2);
            const int d0 = (lane8 & 3) * 16;
            __bf16* gp = outb + ((size_t)(bb * H_ + h) * T + rk) * 64 + d0;
            const float* sp = &fs[r32 * STR + lane8 * 16];
            *(bf16x8*)gp       = cvt8(sp);
            *(bf16x8*)(gp + 8) = cvt8(sp + 8);
        } else {
            // V transposed bf16 [bh][64][TY]
            const int dcol = tid >> 1;
            const int g16  = tid & 1;
            const int h  = ((n0 - C_) >> 6) + (dcol >> 6);
            const int dd = dcol & 63;
            const int kbase = row0 + g16 * 64 + i * 16;
            const int bb  = kbase >> 12;
            const int kin = kbase & (TY_ - 1);
            float tmp[16];
#pragma unroll
            for (int jj = 0; jj < 16; jj++)
                tmp[jj] = fs[(g16 * 16 + jj) * STR + dcol];
            __bf16* gp = Vtb + ((size_t)(bb * H_ + h) * 64 + dd) * TY_ + kin;
            *(bf16x8*)gp       = cvt8(tmp);
            *(bf16x8*)(gp + 8) = cvt8(tmp + 8);
        }
    }
}

// ---------------------------------------------------------------------------
// MFMA flash attention, no-max softmax (scores O(1), shift-invariant).
// Block = 4 waves = 64 q rows; chunk = 32 k; NSPLIT k-splits.
// ---------------------------------------------------------------------------
__global__ __launch_bounds__(256)
void attn_mfma(const __bf16* __restrict__ Qb,
               const __bf16* __restrict__ Kb,
               const __bf16* __restrict__ Vt,
               const float* __restrict__ x_t,
               const float* __restrict__ y_t,
               const int* __restrict__ dist_p,
               const int* __restrict__ min_dist_p,
               float* __restrict__ pacc,
               float* __restrict__ pml)
{
    __shared__ __align__(16) __bf16 Kc[32 * 64];   // [k][d]
    __shared__ __align__(16) __bf16 Vc[64 * 32];   // [d][k]
    __shared__ __align__(16) __bf16 Pt[4][16 * 32];

    const int tid  = threadIdx.x;
    const int wave = tid >> 6;
    const int m16  = tid & 15;
    const int quad = (tid & 63) >> 4;
    const int qt = blockIdx.x, bh = blockIdx.y, split = blockIdx.z;
    const int b = bh / H_;
    const int qblk  = qt * 64;
    const int qbase = qblk + wave * 16;

    const float dist = (float)dist_p[0];
    const float md   = (float)min_dist_p[0];
    const float* yt = y_t + (size_t)b * TY_;
    const float* xt = x_t + (size_t)b * TX_;

    const float xtmin = xt[qblk] - md;
    const float xtmax = xt[qblk + 63] - md;
    int lo = 0, hi = TY_;
    while (lo < hi) { int mid = (lo + hi) >> 1; if (yt[mid] + dist < xtmin) lo = mid + 1; else hi = mid; }
    const int klo = lo;
    lo = 0; hi = TY_;
    while (lo < hi) { int mid = (lo + hi) >> 1; if (yt[mid] <= xtmax) lo = mid + 1; else hi = mid; }
    const int khi = lo - 1;
    const int len = khi - klo + 1;

    int k0 = klo, k1 = klo;
    if (len > 0) {
        const int cnt = (len + NSPLIT - 1) / NSPLIT;
        k0 = klo + split * cnt;
        k1 = min(k0 + cnt, klo + len);
    }

    float xtq[4];
#pragma unroll
    for (int r = 0; r < 4; r++)
        xtq[r] = xt[qbase + quad * 4 + r] - md;

    const __bf16* qp = Qb + ((size_t)bh * TX_ + qbase + m16) * 64;
    const bf16x8 aq0 = *(const bf16x8*)(qp + quad * 8);
    const bf16x8 aq1 = *(const bf16x8*)(qp + 32 + quad * 8);

    float l[4];
    floatx4 o[4];
#pragma unroll
    for (int r = 0; r < 4; r++) l[r] = 0.f;
#pragma unroll
    for (int t = 0; t < 4; t++) o[t] = (floatx4){0.f, 0.f, 0.f, 0.f};

    for (int kc = k0; kc < k1; kc += 32) {
        const float yt0 = yt[min(kc + m16, TY_ - 1)];
        const float yt1 = yt[min(kc + 16 + m16, TY_ - 1)];

        __syncthreads();
        {
            const int krow = tid >> 3;
            const int kg = min(kc + krow, TY_ - 1);
            async_copy16(Kb + ((size_t)bh * TY_ + kg) * 64 + (tid & 7) * 8,
                         (char*)Kc + tid * 16);
            const int d = tid >> 2;
            const int kv = min(kc + (tid & 3) * 8, TY_ - 8);
            async_copy16(Vt + ((size_t)bh * 64 + d) * TY_ + kv,
                         (char*)Vc + tid * 16);
        }
        __syncthreads();

        const bf16x8 bk0h0 = *(const bf16x8*)(Kc + m16 * 64 + quad * 8);
        const bf16x8 bk1h0 = *(const bf16x8*)(Kc + m16 * 64 + 32 + quad * 8);
        const bf16x8 bk0h1 = *(const bf16x8*)(Kc + (16 + m16) * 64 + quad * 8);
        const bf16x8 bk1h1 = *(const bf16x8*)(Kc + (16 + m16) * 64 + 32 + quad * 8);
        floatx4 s0 = (floatx4){0.f, 0.f, 0.f, 0.f};
        floatx4 s1 = (floatx4){0.f, 0.f, 0.f, 0.f};
        s0 = __builtin_amdgcn_mfma_f32_16x16x32_bf16(aq0, bk0h0, s0, 0, 0, 0);
        s0 = __builtin_amdgcn_mfma_f32_16x16x32_bf16(aq1, bk1h0, s0, 0, 0, 0);
        s1 = __builtin_amdgcn_mfma_f32_16x16x32_bf16(aq0, bk0h1, s1, 0, 0, 0);
        s1 = __builtin_amdgcn_mfma_f32_16x16x32_bf16(aq1, bk1h1, s1, 0, 0, 0);

        const int kg0 = kc + m16;
        const int kg1 = kc + 16 + m16;
        __bf16* pt = Pt[wave];
#pragma unroll
        for (int r = 0; r < 4; r++) {
            const bool v0 = (kg0 < k1) && (xtq[r] >= yt0) && (xtq[r] <= yt0 + dist);
            const bool v1 = (kg1 < k1) && (xtq[r] >= yt1) && (xtq[r] <= yt1 + dist);
            const float p0 = v0 ? (float)(__bf16)__expf(s0[r]) : 0.f;
            const float p1 = v1 ? (float)(__bf16)__expf(s1[r]) : 0.f;
            l[r] += p0 + p1;
            pt[(quad * 4 + r) * 32 + m16]      = (__bf16)p0;
            pt[(quad * 4 + r) * 32 + 16 + m16] = (__bf16)p1;
        }
        const bf16x8 ap = *(const bf16x8*)(pt + m16 * 32 + quad * 8);
#pragma unroll
        for (int t = 0; t < 4; t++) {
            const bf16x8 bv = *(const bf16x8*)(Vc + (t * 16 + m16) * 32 + quad * 8);
            o[t] = __builtin_amdgcn_mfma_f32_16x16x32_bf16(ap, bv, o[t], 0, 0, 0);
        }
    }

#pragma unroll
    for (int r = 0; r < 4; r++) {
#pragma unroll
        for (int w = 1; w < 16; w <<= 1)
            l[r] += __shfl_xor(l[r], w);
    }

#pragma unroll
    for (int t = 0; t < 4; t++)
#pragma unroll
        for (int r = 0; r < 4; r++) {
            const size_t gr = (size_t)bh * TX_ + qbase + quad * 4 + r;
            pacc[((size_t)split * R_ + gr) * 64 + t * 16 + m16] = o[t][r];
        }
    if (m16 == 0) {
#pragma unroll
        for (int r = 0; r < 4; r++) {
            const size_t gr = (size_t)bh * TX_ + qbase + quad * 4 + r;
            pml[(size_t)split * R_ + gr] = l[r];
        }
    }
}

// ---------------------------------------------------------------------------
// proj GEMM with FUSED split-combine in the A-staging path:
// A[row][c] = (pacc[0][gr][d] + pacc[1][gr][d]) / (pml[0][gr]+pml[1][gr])
// where gr=(b*H+h)*TX+tx, h=c>>6, d=c&63. B = Wprt via global_load_lds.
// ---------------------------------------------------------------------------
__global__ __launch_bounds__(256)
void gemm_proj(const float* __restrict__ pacc,
               const float* __restrict__ pml,
               const __bf16* __restrict__ Bt,
               float* __restrict__ out0)
{
    __shared__ __align__(16) float smem_f[4224];
    __bf16* As = (__bf16*)smem_f;

    const int tid  = threadIdx.x;
    const int wave = tid >> 6;
    const int lane = tid & 63;
    const int m16  = lane & 15;
    const int quad = lane >> 4;
    const int wm   = wave >> 1;
    const int wn   = wave & 1;
    const int row0 = blockIdx.y * 128;
    const int n0   = blockIdx.x * 128;

    floatx4 acc[4][4];
#pragma unroll
    for (int i = 0; i < 4; i++)
#pragma unroll
        for (int j = 0; j < 4; j++) acc[i][j] = (floatx4){0.f, 0.f, 0.f, 0.f};

    int srow[4], scol[4];
#pragma unroll
    for (int j = 0; j < 4; j++) {
        int e = j * 2048 + wave * 512 + lane * 8;
        int e2 = e & 4095;
        srow[j] = e2 >> 5;
        scol[j] = e2 & 31;
    }

    for (int k0 = 0; k0 < C_; k0 += 32) {
        __syncthreads();
#pragma unroll
        for (int j = 2; j < 4; j++)
            async_copy16(Bt + (size_t)(n0 + srow[j]) * C_ + (k0 + scol[j]),
                         (char*)smem_f + j * 4096 + wave * 1024);
#pragma unroll
        for (int j = 0; j < 2; j++) {
            const int row = row0 + srow[j];
            const int c0  = k0 + scol[j];          // 8-aligned, within one head
            const int bb = row >> 10, tx = row & (TX_ - 1);
            const int h = c0 >> 6, d = c0 & 63;
            const size_t gr = (size_t)(bb * H_ + h) * TX_ + tx;
            const float L = pml[gr] + pml[(size_t)R_ + gr];
            const float inv = (L > 0.f) ? 1.f / L : 0.f;
            const float* p0 = pacc + gr * 64 + d;
            const float* p1 = pacc + ((size_t)R_ + gr) * 64 + d;
            float4 a0 = *(const float4*)p0, a1 = *(const float4*)(p0 + 4);
            float4 b0 = *(const float4*)p1, b1 = *(const float4*)(p1 + 4);
            bf16x8 v;
            v[0] = (__bf16)((a0.x + b0.x) * inv);
            v[1] = (__bf16)((a0.y + b0.y) * inv);
            v[2] = (__bf16)((a0.z + b0.z) * inv);
            v[3] = (__bf16)((a0.w + b0.w) * inv);
            v[4] = (__bf16)((a1.x + b1.x) * inv);
            v[5] = (__bf16)((a1.y + b1.y) * inv);
            v[6] = (__bf16)((a1.z + b1.z) * inv);
            v[7] = (__bf16)((a1.w + b1.w) * inv);
            *(bf16x8*)((char*)smem_f + j * 4096 + wave * 1024 + lane * 16) = v;
        }
        __syncthreads();

        bf16x8 af[4], bfr[4];
#pragma unroll
        for (int i = 0; i < 4; i++)
            af[i] = *(const bf16x8*)(As + (size_t)(wm * 64 + i * 16 + m16) * 32 + quad * 8);
#pragma unroll
        for (int j = 0; j < 4; j++)
            bfr[j] = *(const bf16x8*)(As + 4096 + (size_t)(wn * 64 + j * 16 + m16) * 32 + quad * 8);
#pragma unroll
        for (int i = 0; i < 4; i++)
#pragma unroll
            for (int j = 0; j < 4; j++)
                acc[i][j] = __builtin_amdgcn_mfma_f32_16x16x32_bf16(af[i], bfr[j], acc[i][j], 0, 0, 0);
    }

    const int STR = 132;
    float* fs = smem_f;
#pragma unroll
    for (int i = 0; i < 4; i++) {
        __syncthreads();
#pragma unroll
        for (int j = 0; j < 4; j++) {
            const int col_l = wn * 64 + j * 16 + m16;
#pragma unroll
            for (int r = 0; r < 4; r++)
                fs[(wm * 16 + quad * 4 + r) * STR + col_l] = acc[i][j][r];
        }
        __syncthreads();
        const int r32 = tid >> 3;
        const int lc  = (tid & 7) * 4;
        const int row = row0 + (r32 >> 4) * 64 + i * 16 + (r32 & 15);
        float* gp = out0 + (size_t)row * C_ + n0;
#pragma unroll
        for (int c2 = 0; c2 < 4; c2++) {
            float4 v4 = *(const float4*)&fs[r32 * STR + c2 * 32 + lc];
            *(float4*)(gp + c2 * 32 + lc) = v4;
        }
    }
}

// ---------------------------------------------------------------------------
extern "C" void kernel_launch(void* const* d_in, const int* in_sizes, int n_in,
                              void* d_out, int out_size, void* d_ws, size_t ws_size,
                              hipStream_t stream)
{
    const float* x        = (const float*)d_in[0];
    const float* x_t      = (const float*)d_in[1];
    const float* y        = (const float*)d_in[2];
    const float* y_t      = (const float*)d_in[3];
    const int*   dist     = (const int*)d_in[4];
    const int*   min_dist = (const int*)d_in[5];
    const float* Wq       = (const float*)d_in[6];
    const float* Wkv      = (const float*)d_in[7];
    const float* Wproj    = (const float*)d_in[8];
    const float* inv_freq = (const float*)d_in[9];
    float* out = (float*)d_out;

    const size_t QN = (size_t)B_ * TX_ * C_;
    const size_t KN = (size_t)B_ * TY_ * C_;

    float* ws = (float*)d_ws;
    float* pacc = ws; ws += (size_t)NSPLIT * R_ * 64;
    float* pml  = ws; ws += (size_t)NSPLIT * R_;
    __bf16* bws = (__bf16*)ws;
    __bf16* Wqt   = bws; bws += (size_t)C_ * C_;
    __bf16* Wkvt  = bws; bws += (size_t)C_ * 2 * C_;
    __bf16* Wprt  = bws; bws += (size_t)C_ * C_;
    __bf16* Qbh   = bws; bws += QN;   // [bh][TX][64]
    __bf16* Kbh   = bws; bws += KN;   // [bh][TY][64]
    __bf16* Vtb   = bws; bws += KN;   // [bh][64][TY]

    transp_all<<<dim3(96, 24), dim3(256), 0, stream>>>(
        Wq, Wqt, Wkv, Wkvt, Wproj, Wprt);

    // fused Q + KV GEMM, 1D grid: 96 Q blocks first, then 768 KV blocks
    gemm_qkv<<<dim3(864), dim3(256), 0, stream>>>(
        x, Wqt, y, Wkvt, Qbh, Kbh, Vtb, x_t, y_t, inv_freq);

    attn_mfma<<<dim3(TX_ / 64, B_ * H_, NSPLIT), dim3(256), 0, stream>>>(
        Qbh, Kbh, Vtb, x_t, y_t, dist, min_dist, pacc, pml);

    gemm_proj<<<dim3(C_ / 128, (B_ * TX_) / 128), dim3(256), 0, stream>>>(
        pacc, pml, Wprt, out);
}

// Round 8
// 206.645 us; speedup vs baseline: 1.0933x; 1.0933x over previous
//
#include <hip/hip_runtime.h>
#include <hip/hip_bf16.h>
#include <math.h>

#define B_ 2
#define TX_ 1024
#define TY_ 4096
#define C_ 768
#define H_ 12
#define D_ 64
#define NSPLIT 4
#define R_ (B_ * H_ * TX_)

typedef __bf16 bf16x8 __attribute__((ext_vector_type(8)));
typedef float floatx4 __attribute__((ext_vector_type(4)));

__device__ __forceinline__ void async_copy16(const void* g, void* l) {
    __builtin_amdgcn_global_load_lds(
        (const __attribute__((address_space(1))) unsigned int*)g,
        (__attribute__((address_space(3))) unsigned int*)l,
        16, 0, 0);
}

__device__ __forceinline__ bf16x8 cvt8(const float* s) {
    bf16x8 r;
#pragma unroll
    for (int i = 0; i < 8; i++) r[i] = (__bf16)s[i];
    return r;
}

// ---------------------------------------------------------------------------
// prep: ONE launch doing (a) all 3 weight transposes W(768xN f32)->Wt(Nx768
// bf16) and (b) x,y f32->bf16 conversion.
// blocks [0,2304): transpose (bxr = bid%96: [0,24) Wq x0.125 | [24,72) Wkv |
// [72,96) Wproj; by = bid/96). blocks [2304, 2304+7680): conv.
// ---------------------------------------------------------------------------
__global__ __launch_bounds__(256)
void prep(const float* __restrict__ x,  __bf16* __restrict__ xb,
          const float* __restrict__ y,  __bf16* __restrict__ yb,
          const float* __restrict__ Wq, __bf16* __restrict__ Wqt,
          const float* __restrict__ Wkv,__bf16* __restrict__ Wkvt,
          const float* __restrict__ Wpr,__bf16* __restrict__ Wprt)
{
    __shared__ float tile[32][33];
    const int bid = blockIdx.x;
    if (bid >= 2304) {
        const int cb = bid - 2304;
        const float* src; __bf16* dst; size_t base;
        if (cb < 1536) { src = x; dst = xb; base = (size_t)cb * 1024; }
        else           { src = y; dst = yb; base = (size_t)(cb - 1536) * 1024; }
        const size_t i = base + threadIdx.x * 4;
        float4 v = *(const float4*)(src + i);
        union { __bf16 h[4]; uint2 u; } p;
        p.h[0] = (__bf16)v.x; p.h[1] = (__bf16)v.y;
        p.h[2] = (__bf16)v.z; p.h[3] = (__bf16)v.w;
        *(uint2*)(dst + i) = p.u;
        return;
    }
    const int bxr = bid % 96;
    const int byr = bid / 96;
    const float* W; __bf16* Wt; int N, nb; float scale = 1.0f;
    if (bxr < 24)      { W = Wq;  Wt = Wqt;  N = C_;     nb = bxr;      scale = 0.125f; }
    else if (bxr < 72) { W = Wkv; Wt = Wkvt; N = 2 * C_; nb = bxr - 24; }
    else               { W = Wpr; Wt = Wprt; N = C_;     nb = bxr - 72; }
    const int bx = nb * 32;
    const int by = byr * 32;
    const int tx = threadIdx.x & 31, ty = threadIdx.x >> 5;
#pragma unroll
    for (int i = 0; i < 4; i++)
        tile[ty + i * 8][tx] = W[(size_t)(by + ty + i * 8) * N + bx + tx];
    __syncthreads();
#pragma unroll
    for (int i = 0; i < 4; i++)
        Wt[(size_t)(bx + ty + i * 8) * C_ + by + tx] =
            (__bf16)(tile[tx][ty + i * 8] * scale);
}

// ---------------------------------------------------------------------------
// Fused Q + KV MFMA GEMM, 1D grid 864 blocks (96 Q tiles first, then 768 KV).
// 128x128 tile, TWO 32-k chunks staged per barrier pair (12 iterations of
// effective BK=64) -> half the barrier-drain stalls of the BK=32 loop.
// All staging via global_load_lds width-16 (A is bf16 from prep).
//   bid <  96: Q : rope -> Qbh [bh][TX][64]
//   bid >= 96: KV: n0<C_ rope -> Kbh [bh][TY][64]; n0>=C_ -> Vtb [bh][64][TY]
// ---------------------------------------------------------------------------
__global__ __launch_bounds__(256)
void gemm_qkv(const __bf16* __restrict__ xb, const __bf16* __restrict__ Wqt,
              const __bf16* __restrict__ yb, const __bf16* __restrict__ Wkvt,
              __bf16* __restrict__ Qbh, __bf16* __restrict__ Kbh,
              __bf16* __restrict__ Vtb,
              const float* __restrict__ x_t, const float* __restrict__ y_t,
              const float* __restrict__ inv_freq)
{
    const int bid = blockIdx.x;
    const bool isQ = (bid < 96);
    const __bf16* A; const __bf16* Bt; const float* t_arr;
    int row0, n0, T, TSH;
    if (isQ) {
        A = xb; Bt = Wqt; t_arr = x_t;
        row0 = (bid / 6) * 128; n0 = (bid % 6) * 128; T = TX_; TSH = 10;
    } else {
        const int r = bid - 96;
        A = yb; Bt = Wkvt; t_arr = y_t;
        row0 = (r / 12) * 128; n0 = (r % 12) * 128; T = TY_; TSH = 12;
    }
    const bool isV = (!isQ) && (n0 >= C_);

    __shared__ __align__(16) float smem_f[8192];   // 32768 B: 2 chunks x 16 KB
    __bf16* smem_b = (__bf16*)smem_f;

    const int tid  = threadIdx.x;
    const int wave = tid >> 6;
    const int lane = tid & 63;
    const int m16  = lane & 15;
    const int quad = lane >> 4;
    const int wm   = wave >> 1;
    const int wn   = wave & 1;

    floatx4 acc[4][4];
#pragma unroll
    for (int i = 0; i < 4; i++)
#pragma unroll
        for (int j = 0; j < 4; j++) acc[i][j] = (floatx4){0.f, 0.f, 0.f, 0.f};

    int srow[4], scol[4];
#pragma unroll
    for (int j = 0; j < 4; j++) {
        int e = j * 2048 + wave * 512 + lane * 8;
        int e2 = e & 4095;
        srow[j] = e2 >> 5;
        scol[j] = e2 & 31;
    }

    for (int k0 = 0; k0 < C_; k0 += 64) {
        __syncthreads();
#pragma unroll
        for (int c = 0; c < 2; c++) {
            const int kk = k0 + c * 32;
#pragma unroll
            for (int j = 0; j < 4; j++) {
                const __bf16* src = (j < 2)
                    ? A  + (size_t)(row0 + srow[j]) * C_ + (kk + scol[j])
                    : Bt + (size_t)(n0   + srow[j]) * C_ + (kk + scol[j]);
                async_copy16(src, (char*)smem_f + c * 16384 + j * 4096 + wave * 1024);
            }
        }
        __syncthreads();

#pragma unroll
        for (int c = 0; c < 2; c++) {
            const __bf16* As = smem_b + c * 8192;
            const __bf16* Bs = As + 4096;
            bf16x8 af[4], bfr[4];
#pragma unroll
            for (int i = 0; i < 4; i++)
                af[i] = *(const bf16x8*)(As + (size_t)(wm * 64 + i * 16 + m16) * 32 + quad * 8);
#pragma unroll
            for (int j = 0; j < 4; j++)
                bfr[j] = *(const bf16x8*)(Bs + (size_t)(wn * 64 + j * 16 + m16) * 32 + quad * 8);
#pragma unroll
            for (int i = 0; i < 4; i++)
#pragma unroll
                for (int j = 0; j < 4; j++)
                    acc[i][j] = __builtin_amdgcn_mfma_f32_16x16x32_bf16(af[i], bfr[j], acc[i][j], 0, 0, 0);
        }
    }

    // ---- epilogue (LDS-staged, full-line stores) ----
    const int STR = 132;
    float* fs = smem_f;

#pragma unroll
    for (int i = 0; i < 4; i++) {
        __syncthreads();
#pragma unroll
        for (int j = 0; j < 4; j++) {
            const int col_l = wn * 64 + j * 16 + m16;
#pragma unroll
            for (int r = 0; r < 4; r++) {
                const int row_l = quad * 4 + r;
                float v = acc[i][j][r];
                if (!isV) {
                    const float vp = __shfl_xor(v, 1);
                    const int row = row0 + wm * 64 + i * 16 + row_l;
                    const int cc = (n0 + col_l) & (D_ - 1);
                    const float fr = t_arr[row] * inv_freq[cc >> 1];
                    const float sn = __sinf(fr), cs = __cosf(fr);
                    v = (m16 & 1) ? (v * cs + vp * sn) : (v * cs - vp * sn);
                }
                fs[(wm * 16 + row_l) * STR + col_l] = v;
            }
        }
        __syncthreads();

        if (!isV) {
            __bf16* outb = isQ ? Qbh : Kbh;
            const int r32 = tid >> 3;
            const int lane8 = tid & 7;
            const int grow = row0 + (r32 >> 4) * 64 + i * 16 + (r32 & 15);
            const int bb = grow >> TSH;
            const int rk = grow & (T - 1);
            const int h  = (n0 >> 6) + (lane8 >> 2);
            const int d0 = (lane8 & 3) * 16;
            __bf16* gp = outb + ((size_t)(bb * H_ + h) * T + rk) * 64 + d0;
            const float* sp = &fs[r32 * STR + lane8 * 16];
            *(bf16x8*)gp       = cvt8(sp);
            *(bf16x8*)(gp + 8) = cvt8(sp + 8);
        } else {
            const int dcol = tid >> 1;
            const int g16  = tid & 1;
            const int h  = ((n0 - C_) >> 6) + (dcol >> 6);
            const int dd = dcol & 63;
            const int kbase = row0 + g16 * 64 + i * 16;
            const int bb  = kbase >> 12;
            const int kin = kbase & (TY_ - 1);
            float tmp[16];
#pragma unroll
            for (int jj = 0; jj < 16; jj++)
                tmp[jj] = fs[(g16 * 16 + jj) * STR + dcol];
            __bf16* gp = Vtb + ((size_t)(bb * H_ + h) * 64 + dd) * TY_ + kin;
            *(bf16x8*)gp       = cvt8(tmp);
            *(bf16x8*)(gp + 8) = cvt8(tmp + 8);
        }
    }
}

// ---------------------------------------------------------------------------
// MFMA flash attention, no-max softmax. Block = 4 waves = 64 q rows;
// chunk = 32 k; NSPLIT k-splits.
// ---------------------------------------------------------------------------
__global__ __launch_bounds__(256)
void attn_mfma(const __bf16* __restrict__ Qb,
               const __bf16* __restrict__ Kb,
               const __bf16* __restrict__ Vt,
               const float* __restrict__ x_t,
               const float* __restrict__ y_t,
               const int* __restrict__ dist_p,
               const int* __restrict__ min_dist_p,
               float* __restrict__ pacc,
               float* __restrict__ pml)
{
    __shared__ __align__(16) __bf16 Kc[32 * 64];
    __shared__ __align__(16) __bf16 Vc[64 * 32];
    __shared__ __align__(16) __bf16 Pt[4][16 * 32];

    const int tid  = threadIdx.x;
    const int wave = tid >> 6;
    const int m16  = tid & 15;
    const int quad = (tid & 63) >> 4;
    const int qt = blockIdx.x, bh = blockIdx.y, split = blockIdx.z;
    const int b = bh / H_;
    const int qblk  = qt * 64;
    const int qbase = qblk + wave * 16;

    const float dist = (float)dist_p[0];
    const float md   = (float)min_dist_p[0];
    const float* yt = y_t + (size_t)b * TY_;
    const float* xt = x_t + (size_t)b * TX_;

    const float xtmin = xt[qblk] - md;
    const float xtmax = xt[qblk + 63] - md;
    int lo = 0, hi = TY_;
    while (lo < hi) { int mid = (lo + hi) >> 1; if (yt[mid] + dist < xtmin) lo = mid + 1; else hi = mid; }
    const int klo = lo;
    lo = 0; hi = TY_;
    while (lo < hi) { int mid = (lo + hi) >> 1; if (yt[mid] <= xtmax) lo = mid + 1; else hi = mid; }
    const int khi = lo - 1;
    const int len = khi - klo + 1;

    int k0 = klo, k1 = klo;
    if (len > 0) {
        const int cnt = (len + NSPLIT - 1) / NSPLIT;
        k0 = klo + split * cnt;
        k1 = min(k0 + cnt, klo + len);
    }

    float xtq[4];
#pragma unroll
    for (int r = 0; r < 4; r++)
        xtq[r] = xt[qbase + quad * 4 + r] - md;

    const __bf16* qp = Qb + ((size_t)bh * TX_ + qbase + m16) * 64;
    const bf16x8 aq0 = *(const bf16x8*)(qp + quad * 8);
    const bf16x8 aq1 = *(const bf16x8*)(qp + 32 + quad * 8);

    float l[4];
    floatx4 o[4];
#pragma unroll
    for (int r = 0; r < 4; r++) l[r] = 0.f;
#pragma unroll
    for (int t = 0; t < 4; t++) o[t] = (floatx4){0.f, 0.f, 0.f, 0.f};

    for (int kc = k0; kc < k1; kc += 32) {
        const float yt0 = yt[min(kc + m16, TY_ - 1)];
        const float yt1 = yt[min(kc + 16 + m16, TY_ - 1)];

        __syncthreads();
        {
            const int krow = tid >> 3;
            const int kg = min(kc + krow, TY_ - 1);
            async_copy16(Kb + ((size_t)bh * TY_ + kg) * 64 + (tid & 7) * 8,
                         (char*)Kc + tid * 16);
            const int d = tid >> 2;
            const int kv = min(kc + (tid & 3) * 8, TY_ - 8);
            async_copy16(Vt + ((size_t)bh * 64 + d) * TY_ + kv,
                         (char*)Vc + tid * 16);
        }
        __syncthreads();

        const bf16x8 bk0h0 = *(const bf16x8*)(Kc + m16 * 64 + quad * 8);
        const bf16x8 bk1h0 = *(const bf16x8*)(Kc + m16 * 64 + 32 + quad * 8);
        const bf16x8 bk0h1 = *(const bf16x8*)(Kc + (16 + m16) * 64 + quad * 8);
        const bf16x8 bk1h1 = *(const bf16x8*)(Kc + (16 + m16) * 64 + 32 + quad * 8);
        floatx4 s0 = (floatx4){0.f, 0.f, 0.f, 0.f};
        floatx4 s1 = (floatx4){0.f, 0.f, 0.f, 0.f};
        s0 = __builtin_amdgcn_mfma_f32_16x16x32_bf16(aq0, bk0h0, s0, 0, 0, 0);
        s0 = __builtin_amdgcn_mfma_f32_16x16x32_bf16(aq1, bk1h0, s0, 0, 0, 0);
        s1 = __builtin_amdgcn_mfma_f32_16x16x32_bf16(aq0, bk0h1, s1, 0, 0, 0);
        s1 = __builtin_amdgcn_mfma_f32_16x16x32_bf16(aq1, bk1h1, s1, 0, 0, 0);

        const int kg0 = kc + m16;
        const int kg1 = kc + 16 + m16;
        __bf16* pt = Pt[wave];
#pragma unroll
        for (int r = 0; r < 4; r++) {
            const bool v0 = (kg0 < k1) && (xtq[r] >= yt0) && (xtq[r] <= yt0 + dist);
            const bool v1 = (kg1 < k1) && (xtq[r] >= yt1) && (xtq[r] <= yt1 + dist);
            const float p0 = v0 ? (float)(__bf16)__expf(s0[r]) : 0.f;
            const float p1 = v1 ? (float)(__bf16)__expf(s1[r]) : 0.f;
            l[r] += p0 + p1;
            pt[(quad * 4 + r) * 32 + m16]      = (__bf16)p0;
            pt[(quad * 4 + r) * 32 + 16 + m16] = (__bf16)p1;
        }
        const bf16x8 ap = *(const bf16x8*)(pt + m16 * 32 + quad * 8);
#pragma unroll
        for (int t = 0; t < 4; t++) {
            const bf16x8 bv = *(const bf16x8*)(Vc + (t * 16 + m16) * 32 + quad * 8);
            o[t] = __builtin_amdgcn_mfma_f32_16x16x32_bf16(ap, bv, o[t], 0, 0, 0);
        }
    }

#pragma unroll
    for (int r = 0; r < 4; r++) {
#pragma unroll
        for (int w = 1; w < 16; w <<= 1)
            l[r] += __shfl_xor(l[r], w);
    }

#pragma unroll
    for (int t = 0; t < 4; t++)
#pragma unroll
        for (int r = 0; r < 4; r++) {
            const size_t gr = (size_t)bh * TX_ + qbase + quad * 4 + r;
            pacc[((size_t)split * R_ + gr) * 64 + t * 16 + m16] = o[t][r];
        }
    if (m16 == 0) {
#pragma unroll
        for (int r = 0; r < 4; r++) {
            const size_t gr = (size_t)bh * TX_ + qbase + quad * 4 + r;
            pml[(size_t)split * R_ + gr] = l[r];
        }
    }
}

// ---------------------------------------------------------------------------
// Combine NSPLIT partials -> Ob bf16 (B,TX,C)
// ---------------------------------------------------------------------------
__global__ __launch_bounds__(256)
void combine_kernel(const float* __restrict__ pacc,
                    const float* __restrict__ pml,
                    __bf16* __restrict__ O)
{
    const int d   = threadIdx.x;
    const int sub = threadIdx.y;
    const size_t r = (size_t)blockIdx.x * 4 + sub;
    const int bh  = (int)(r / TX_);
    const int txg = (int)(r % TX_);
    const int b = bh / H_, h = bh % H_;

    float L = 0.f, val = 0.f;
#pragma unroll
    for (int s = 0; s < NSPLIT; s++) {
        L   += pml[(size_t)s * R_ + r];
        val += pacc[((size_t)s * R_ + r) * 64 + d];
    }
    const float o = (L > 0.f) ? val / L : 0.f;
    O[(size_t)(b * TX_ + txg) * C_ + h * D_ + d] = (__bf16)o;
}

// ---------------------------------------------------------------------------
// proj GEMM: out(M,768 f32) = A(M,768 bf16) @ Bt(768,768 bf16)^T
// ---------------------------------------------------------------------------
__global__ __launch_bounds__(256)
void gemm_proj(const __bf16* __restrict__ A,
               const __bf16* __restrict__ Bt,
               float* __restrict__ out0)
{
    __shared__ __align__(16) float smem_f[8192];
    __bf16* smem_b = (__bf16*)smem_f;

    const int tid  = threadIdx.x;
    const int wave = tid >> 6;
    const int lane = tid & 63;
    const int m16  = lane & 15;
    const int quad = lane >> 4;
    const int wm   = wave >> 1;
    const int wn   = wave & 1;
    const int row0 = blockIdx.y * 128;
    const int n0   = blockIdx.x * 128;

    floatx4 acc[4][4];
#pragma unroll
    for (int i = 0; i < 4; i++)
#pragma unroll
        for (int j = 0; j < 4; j++) acc[i][j] = (floatx4){0.f, 0.f, 0.f, 0.f};

    int srow[4], scol[4];
#pragma unroll
    for (int j = 0; j < 4; j++) {
        int e = j * 2048 + wave * 512 + lane * 8;
        int e2 = e & 4095;
        srow[j] = e2 >> 5;
        scol[j] = e2 & 31;
    }

    for (int k0 = 0; k0 < C_; k0 += 64) {
        __syncthreads();
#pragma unroll
        for (int c = 0; c < 2; c++) {
            const int kk = k0 + c * 32;
#pragma unroll
            for (int j = 0; j < 4; j++) {
                const __bf16* src = (j < 2)
                    ? A  + (size_t)(row0 + srow[j]) * C_ + (kk + scol[j])
                    : Bt + (size_t)(n0   + srow[j]) * C_ + (kk + scol[j]);
                async_copy16(src, (char*)smem_f + c * 16384 + j * 4096 + wave * 1024);
            }
        }
        __syncthreads();

#pragma unroll
        for (int c = 0; c < 2; c++) {
            const __bf16* As = smem_b + c * 8192;
            const __bf16* Bs = As + 4096;
            bf16x8 af[4], bfr[4];
#pragma unroll
            for (int i = 0; i < 4; i++)
                af[i] = *(const bf16x8*)(As + (size_t)(wm * 64 + i * 16 + m16) * 32 + quad * 8);
#pragma unroll
            for (int j = 0; j < 4; j++)
                bfr[j] = *(const bf16x8*)(Bs + (size_t)(wn * 64 + j * 16 + m16) * 32 + quad * 8);
#pragma unroll
            for (int i = 0; i < 4; i++)
#pragma unroll
                for (int j = 0; j < 4; j++)
                    acc[i][j] = __builtin_amdgcn_mfma_f32_16x16x32_bf16(af[i], bfr[j], acc[i][j], 0, 0, 0);
        }
    }

    const int STR = 132;
    float* fs = smem_f;
#pragma unroll
    for (int i = 0; i < 4; i++) {
        __syncthreads();
#pragma unroll
        for (int j = 0; j < 4; j++) {
            const int col_l = wn * 64 + j * 16 + m16;
#pragma unroll
            for (int r = 0; r < 4; r++)
                fs[(wm * 16 + quad * 4 + r) * STR + col_l] = acc[i][j][r];
        }
        __syncthreads();
        const int r32 = tid >> 3;
        const int lc  = (tid & 7) * 4;
        const int row = row0 + (r32 >> 4) * 64 + i * 16 + (r32 & 15);
        float* gp = out0 + (size_t)row * C_ + n0;
#pragma unroll
        for (int c2 = 0; c2 < 4; c2++) {
            float4 v4 = *(const float4*)&fs[r32 * STR + c2 * 32 + lc];
            *(float4*)(gp + c2 * 32 + lc) = v4;
        }
    }
}

// ---------------------------------------------------------------------------
extern "C" void kernel_launch(void* const* d_in, const int* in_sizes, int n_in,
                              void* d_out, int out_size, void* d_ws, size_t ws_size,
                              hipStream_t stream)
{
    const float* x        = (const float*)d_in[0];
    const float* x_t      = (const float*)d_in[1];
    const float* y        = (const float*)d_in[2];
    const float* y_t      = (const float*)d_in[3];
    const int*   dist     = (const int*)d_in[4];
    const int*   min_dist = (const int*)d_in[5];
    const float* Wq       = (const float*)d_in[6];
    const float* Wkv      = (const float*)d_in[7];
    const float* Wproj    = (const float*)d_in[8];
    const float* inv_freq = (const float*)d_in[9];
    float* out = (float*)d_out;

    const size_t QN = (size_t)B_ * TX_ * C_;
    const size_t KN = (size_t)B_ * TY_ * C_;

    float* ws = (float*)d_ws;
    float* pacc = ws; ws += (size_t)NSPLIT * R_ * 64;
    float* pml  = ws; ws += (size_t)NSPLIT * R_;
    __bf16* bws = (__bf16*)ws;
    __bf16* xb    = bws; bws += QN;
    __bf16* yb    = bws; bws += KN;
    __bf16* Wqt   = bws; bws += (size_t)C_ * C_;
    __bf16* Wkvt  = bws; bws += (size_t)C_ * 2 * C_;
    __bf16* Wprt  = bws; bws += (size_t)C_ * C_;
    __bf16* Ob    = bws; bws += QN;
    __bf16* Qbh   = bws; bws += QN;   // [bh][TX][64]
    __bf16* Kbh   = bws; bws += KN;   // [bh][TY][64]
    __bf16* Vtb   = bws; bws += KN;   // [bh][64][TY]

    // prep: weight transposes + x/y bf16 conversion, one launch
    prep<<<dim3(2304 + 7680), dim3(256), 0, stream>>>(
        x, xb, y, yb, Wq, Wqt, Wkv, Wkvt, Wproj, Wprt);

    // fused Q + KV GEMM, 1D grid: 96 Q blocks first, then 768 KV blocks
    gemm_qkv<<<dim3(864), dim3(256), 0, stream>>>(
        xb, Wqt, yb, Wkvt, Qbh, Kbh, Vtb, x_t, y_t, inv_freq);

    attn_mfma<<<dim3(TX_ / 64, B_ * H_, NSPLIT), dim3(256), 0, stream>>>(
        Qbh, Kbh, Vtb, x_t, y_t, dist, min_dist, pacc, pml);

    combine_kernel<<<dim3((unsigned)(R_ / 4)), dim3(64, 4), 0, stream>>>(
        pacc, pml, Ob);

    gemm_proj<<<dim3(C_ / 128, (B_ * TX_) / 128), dim3(256), 0, stream>>>(
        Ob, Wprt, out);
}